// Round 2
// baseline (385.217 us; speedup 1.0000x reference)
//
#include <hip/hip_runtime.h>

// UpSample1d (ratio=2), closed-form polyphase (verified vs reference round 1):
//   out[2s]   = 2*(f1*x[s+2]+f3*x[s+1]+f5*x[s]+f7*x[s-1]+f9*x[s-2]+f11*x[s-3])
//   out[2s+1] = 2*(f0*x[s+3]+f2*x[s+2]+f4*x[s+1]+f6*x[s]+f8*x[s-1]+f10*x[s-2])
// with edge-clamped x (replicate pad).
//
// v2: one thread per s-position. Dense 4B/lane loads (7 taps, L1 absorbs the
// overlap), 12 FMAs, one dense 8B/lane float2 store. No register arrays, no
// grid-stride loop, no strided stores.

constexpr int T_IN  = 8192;
constexpr int T_OUT = 16384;

__global__ __launch_bounds__(256)
void upsample2x_v2(const float* __restrict__ x,
                   const float* __restrict__ filt,
                   float* __restrict__ out,
                   int total)
{
    int w = blockIdx.x * blockDim.x + threadIdx.x;
    if (w >= total) return;

    int row = w >> 13;            // w / T_IN
    int s   = w & (T_IN - 1);     // w % T_IN

    const float* xr = x + ((long long)row << 13);

    // Taps: uniform address -> scalar loads (compiler emits s_load).
    float f0 = filt[0],  f1 = filt[1],  f2  = filt[2],  f3  = filt[3];
    float f4 = filt[4],  f5 = filt[5],  f6  = filt[6],  f7  = filt[7];
    float f8 = filt[8],  f9 = filt[9],  f10 = filt[10], f11 = filt[11];

    float xm3, xm2, xm1, x0, xp1, xp2, xp3;
    if (s >= 3 && s <= T_IN - 4) {
        // Interior fast path: 7 dense scalar loads.
        xm3 = xr[s - 3]; xm2 = xr[s - 2]; xm1 = xr[s - 1];
        x0  = xr[s];
        xp1 = xr[s + 1]; xp2 = xr[s + 2]; xp3 = xr[s + 3];
    } else {
        // Row edges (6 lanes per row): clamped loads (replicate padding).
        int im3 = s - 3 < 0 ? 0 : s - 3;
        int im2 = s - 2 < 0 ? 0 : s - 2;
        int im1 = s - 1 < 0 ? 0 : s - 1;
        int ip1 = s + 1 > T_IN - 1 ? T_IN - 1 : s + 1;
        int ip2 = s + 2 > T_IN - 1 ? T_IN - 1 : s + 2;
        int ip3 = s + 3 > T_IN - 1 ? T_IN - 1 : s + 3;
        xm3 = xr[im3]; xm2 = xr[im2]; xm1 = xr[im1];
        x0  = xr[s];
        xp1 = xr[ip1]; xp2 = xr[ip2]; xp3 = xr[ip3];
    }

    float ev = f1 * xp2 + f3 * xp1 + f5  * x0
             + f7 * xm1 + f9 * xm2 + f11 * xm3;
    float od = f0 * xp3 + f2 * xp2 + f4  * xp1
             + f6 * x0  + f8 * xm1 + f10 * xm2;

    float2 o = make_float2(2.0f * ev, 2.0f * od);
    *(float2*)(out + ((long long)row << 14) + 2 * s) = o;
}

extern "C" void kernel_launch(void* const* d_in, const int* in_sizes, int n_in,
                              void* d_out, int out_size, void* d_ws, size_t ws_size,
                              hipStream_t stream) {
    const float* x    = (const float*)d_in[0];
    const float* filt = (const float*)d_in[1];
    float* out        = (float*)d_out;

    int rows  = in_sizes[0] / T_IN;   // 8*512 = 4096
    int total = rows * T_IN;          // 33,554,432 s-positions

    const int block = 256;
    int grid = (total + block - 1) / block;   // 131072 blocks
    upsample2x_v2<<<grid, block, 0, stream>>>(x, filt, out, total);
}